// Round 2
// baseline (96.821 us; speedup 1.0000x reference)
//
#include <hip/hip_runtime.h>
#include <hip/hip_bf16.h>

// Outputs concatenated flat (fp32):
//   [0, 4L)            input_tensor [L,4] = {x,y,z,onehot}
//   [4L, 4L+3B)        closest_points [B,3]
//   [4L+3B, 4L+4B)     min_index [B] (as float)
// B = 128, L = 1e6 (derived at launch).

#define NRECV 128
#define TILE 512
#define BLK 256
#define NGRP 4  // point-classes = BLK/64; each thread owns 2 receivers

typedef unsigned long long u64;

// Stage 1: grid-stride over point tiles. Each block:
//   - stages tile into LDS as float4{x,y,z,0}
//   - (fused) writes out[L,4] = {x,y,z,0} for the tile
//   - each thread: 2 receivers (c, c+64), points p == g (mod 4), g = wave id
//   - merge per-block best (u64 key = d2bits<<32 | idx) -> stage[block][recv]
__global__ __launch_bounds__(BLK) void k_argmin_fill(
    const float* __restrict__ pts, const float* __restrict__ recv,
    u64* __restrict__ stage, float* __restrict__ out, int L, int ntiles) {
  __shared__ float4 sp4[TILE];
  __shared__ u64 sm[NGRP][NRECV];

  const int tid = threadIdx.x;
  const int g = tid >> 6;    // point-class (uniform within wave)
  const int c = tid & 63;    // receiver lane

  const float rx0 = recv[c * 3 + 0];
  const float ry0 = recv[c * 3 + 1];
  const float rz0 = recv[c * 3 + 2];
  const float rx1 = recv[(c + 64) * 3 + 0];
  const float ry1 = recv[(c + 64) * 3 + 1];
  const float rz1 = recv[(c + 64) * 3 + 2];

  float b0 = 3.4e38f, b1 = 3.4e38f;
  int i0 = 0, i1 = 0;

  for (int t = blockIdx.x; t < ntiles; t += gridDim.x) {
    const int base = t * TILE;
    const int cnt = min(TILE, L - base);

    // Stage tile to LDS + fused output fill {x,y,z,0}.
    for (int q = tid; q < cnt; q += BLK) {
      const int gi = base + q;
      float4 v;
      v.x = pts[3 * gi + 0];
      v.y = pts[3 * gi + 1];
      v.z = pts[3 * gi + 2];
      v.w = 0.0f;
      sp4[q] = v;
      reinterpret_cast<float4*>(out)[gi] = v;
    }
    __syncthreads();

    // All 64 lanes of a wave read the same p -> LDS broadcast (conflict-free).
#pragma unroll 4
    for (int p = g; p < cnt; p += NGRP) {
      const float4 q = sp4[p];
      const float dx0 = q.x - rx0, dy0 = q.y - ry0, dz0 = q.z - rz0;
      const float d0 = fmaf(dz0, dz0, fmaf(dy0, dy0, dx0 * dx0));
      const float dx1 = q.x - rx1, dy1 = q.y - ry1, dz1 = q.z - rz1;
      const float d1 = fmaf(dz1, dz1, fmaf(dy1, dy1, dx1 * dx1));
      const bool c0 = d0 < b0;  // strict < + increasing p => lowest idx on tie
      b0 = c0 ? d0 : b0;
      i0 = c0 ? (base + p) : i0;
      const bool c1 = d1 < b1;
      b1 = c1 ? d1 : b1;
      i1 = c1 ? (base + p) : i1;
    }
    __syncthreads();
  }

  // Merge the 4 point-classes per receiver. d2 >= 0 so raw float bits are
  // order-monotone; key min == (d2, then lowest index) min.
  sm[g][c] = ((u64)__float_as_uint(b0) << 32) | (unsigned int)i0;
  sm[g][c + 64] = ((u64)__float_as_uint(b1) << 32) | (unsigned int)i1;
  __syncthreads();
  if (tid < NRECV) {
    u64 best = sm[0][tid];
#pragma unroll
    for (int k = 1; k < NGRP; ++k) {
      u64 o = sm[k][tid];
      best = o < best ? o : best;
    }
    stage[(size_t)blockIdx.x * NRECV + tid] = best;
  }
}

// Stage 2: one block per receiver. Reduce per-block bests, emit outputs,
// scatter one-hot (stage-1 zeroed the column; stream order guarantees it).
__global__ __launch_bounds__(BLK) void k_finalize(
    const u64* __restrict__ stage, int nblocks,
    const float* __restrict__ pts, float* __restrict__ out, int L) {
  const int r = blockIdx.x;
  const int tid = threadIdx.x;

  u64 best = ~0ull;
  for (int j = tid; j < nblocks; j += BLK) {
    u64 k = stage[(size_t)j * NRECV + r];
    best = k < best ? k : best;
  }
  for (int off = 32; off > 0; off >>= 1) {
    u64 o = __shfl_down(best, off);
    best = o < best ? o : best;
  }
  __shared__ u64 w[BLK / 64];
  if ((tid & 63) == 0) w[tid >> 6] = best;
  __syncthreads();
  if (tid == 0) {
#pragma unroll
    for (int i = 1; i < BLK / 64; ++i) {
      u64 o = w[i];
      best = o < best ? o : best;
    }
    const unsigned int idx = (unsigned int)(best & 0xffffffffu);
    const size_t Lo = (size_t)L * 4;
    out[Lo + (size_t)r * 3 + 0] = pts[(size_t)idx * 3 + 0];
    out[Lo + (size_t)r * 3 + 1] = pts[(size_t)idx * 3 + 1];
    out[Lo + (size_t)r * 3 + 2] = pts[(size_t)idx * 3 + 2];
    out[Lo + (size_t)NRECV * 3 + r] = (float)idx;  // min_index as float
    out[(size_t)idx * 4 + 3] = 1.0f;               // one-hot (benign race)
    if (r == 0) out[3] = 1.0f;  // reference quirk: B>1 also sets index 0
  }
}

extern "C" void kernel_launch(void* const* d_in, const int* in_sizes, int n_in,
                              void* d_out, int out_size, void* d_ws, size_t ws_size,
                              hipStream_t stream) {
  const float* pts = (const float*)d_in[0];   // [L,3]
  const float* recv = (const float*)d_in[1];  // [128,3]
  float* out = (float*)d_out;

  const int L = in_sizes[0] / 3;
  const int ntiles = (L + TILE - 1) / TILE;

  int nb1 = 1024;
  if ((size_t)nb1 * NRECV * sizeof(u64) > ws_size) {
    nb1 = (int)(ws_size / (NRECV * sizeof(u64)));
    if (nb1 < 1) nb1 = 1;
  }
  if (nb1 > ntiles) nb1 = ntiles;

  u64* stage = (u64*)d_ws;

  k_argmin_fill<<<nb1, BLK, 0, stream>>>(pts, recv, stage, out, L, ntiles);
  k_finalize<<<NRECV, BLK, 0, stream>>>(stage, nb1, pts, out, L);
}